// Round 10
// baseline (141.712 us; speedup 1.0000x reference)
//
#include <hip/hip_runtime.h>
#include <math.h>
#include <float.h>

#define E_DIM 128
typedef unsigned short ushort_t;
typedef __bf16 bf16x8 __attribute__((ext_vector_type(8)));
typedef float  f32x4  __attribute__((ext_vector_type(4)));

__device__ inline ushort_t f2bf(float f) {
    union { float f; unsigned int u; } x; x.f = f;
    unsigned int r = x.u + 0x7fffu + ((x.u >> 16) & 1u);   // RNE
    return (ushort_t)(r >> 16);
}
__device__ inline float bf2f(unsigned int hi16) {
    union { unsigned int u; float f; } x; x.u = hi16 << 16;
    return x.f;
}
__device__ inline void lexmin(float& d, int& i, float d2, int i2) {
    if (d2 < d || (d2 == d && i2 < i)) { d = d2; i = i2; }
}

// ---- MFMA tile helpers (64 rows x 128 cols, 4 waves, LDS XOR-swizzled) ----
__device__ inline void stage_A_f32(char* AsmB, const float* abase, const float* fake,
                                   bool ign, int tid) {
#pragma unroll
    for (int i = 0; i < 8; ++i) {
        int f = (tid + i * 256) * 4;
        int r = f >> 7, c = f & 127;
        float4 v = *(const float4*)(ign ? (fake + c) : (abase + f));
        unsigned int lo = (unsigned int)f2bf(v.x) | ((unsigned int)f2bf(v.y) << 16);
        unsigned int hi = (unsigned int)f2bf(v.z) | ((unsigned int)f2bf(v.w) << 16);
        *(uint2*)(AsmB + r * 256 + ((c * 2) ^ ((r & 7) << 4))) = make_uint2(lo, hi);
    }
}

// stage pre-transposed bf16 W (n-major [128][128]) -> swizzled LDS (256 thr)
__device__ inline void stage_WT(char* WsmB, const ushort_t* Wt, int tid) {
#pragma unroll
    for (int i = 0; i < 8; ++i) {
        int gb = (tid + i * 256) * 16;
        int n = gb >> 8, cb = gb & 255;
        uint4 v = *(const uint4*)((const char*)Wt + gb);
        *(uint4*)(WsmB + n * 256 + (cb ^ ((n & 7) << 4))) = v;
    }
}

__device__ inline void mma_16x128(char* AsmB, char* WsmB, int wv, int lane, f32x4 acc[8]) {
    int l15 = lane & 15, kg = lane >> 4;
    int r = wv * 16 + l15;
#pragma unroll
    for (int kc = 0; kc < 4; ++kc) {
        int kb = (kc * 32 + kg * 8) * 2;
        bf16x8 a = *(const bf16x8*)(AsmB + r * 256 + (kb ^ ((r & 7) << 4)));
#pragma unroll
        for (int nf = 0; nf < 8; ++nf) {
            int n = nf * 16 + l15;
            bf16x8 b = *(const bf16x8*)(WsmB + n * 256 + (kb ^ ((n & 7) << 4)));
            acc[nf] = __builtin_amdgcn_mfma_f32_16x16x32_bf16(a, b, acc[nf], 0, 0, 0);
        }
    }
}

__device__ inline void mma_16x128_dual(char* AsmB, char* Wsm0B, char* Wsm1B,
                                       int wv, int lane, f32x4 acc0[8], f32x4 acc1[8]) {
    int l15 = lane & 15, kg = lane >> 4;
    int r = wv * 16 + l15;
#pragma unroll
    for (int kc = 0; kc < 4; ++kc) {
        int kb = (kc * 32 + kg * 8) * 2;
        bf16x8 a = *(const bf16x8*)(AsmB + r * 256 + (kb ^ ((r & 7) << 4)));
#pragma unroll
        for (int nf = 0; nf < 8; ++nf) {
            int n = nf * 16 + l15;
            int nb = (kb ^ ((n & 7) << 4));
            bf16x8 b0 = *(const bf16x8*)(Wsm0B + n * 256 + nb);
            acc0[nf] = __builtin_amdgcn_mfma_f32_16x16x32_bf16(a, b0, acc0[nf], 0, 0, 0);
            bf16x8 b1 = *(const bf16x8*)(Wsm1B + n * 256 + nb);
            acc1[nf] = __builtin_amdgcn_mfma_f32_16x16x32_bf16(a, b1, acc1[nf], 0, 0, 0);
        }
    }
}

__device__ inline void epi_bf16(ushort_t* C, int row0, int wv, int lane, f32x4 acc[8]) {
    int l15 = lane & 15, kg = lane >> 4;
    int rbase = row0 + wv * 16 + kg * 4;
#pragma unroll
    for (int rr = 0; rr < 4; ++rr) {
        ushort_t* dst = C + (size_t)(rbase + rr) * E_DIM + l15;
#pragma unroll
        for (int nf = 0; nf < 8; ++nf) dst[nf * 16] = f2bf(acc[nf][rr]);
    }
}

#define ZERO_ACC(a) do { _Pragma("unroll") for (int _i = 0; _i < 8; ++_i) \
    (a)[_i] = (f32x4){0.f, 0.f, 0.f, 0.f}; } while (0)

// ---------------------------------------------------------------------------
// K1: blocks [0, NB): nearest (L1 argmin, first-min tie-break)
//     blocks [NB, NB+64): fp32->bf16 n-major weight transpose
// ---------------------------------------------------------------------------
__global__ __launch_bounds__(256) void pre_kernel(
        const float* __restrict__ xc_off, const float* __restrict__ xc_on,
        const float* __restrict__ Wq, const float* __restrict__ Wk,
        const float* __restrict__ Wv, const float* __restrict__ Wo,
        ushort_t* __restrict__ WT, int* __restrict__ nearest, int U, int S, int B) {
    __shared__ __align__(16) char smraw[36928];
    const int NB = (U / 32) * B;
    int bid = blockIdx.x;
    int tid = threadIdx.x;
    if (bid >= NB) {
        int base = (bid - NB) * 1024 + tid;
#pragma unroll
        for (int j = 0; j < 4; ++j) {
            int idx = base + j * 256;
            int w = idx >> 14;
            int rem = idx & 16383;
            int k = rem >> 7, n = rem & 127;
            const float* src = (w == 0) ? Wq : (w == 1) ? Wk : (w == 2) ? Wv : Wo;
            WT[(size_t)w * 16384 + n * E_DIM + k] = f2bf(src[k * E_DIM + n]);
        }
        return;
    }
    float4* on = (float4*)smraw;                          // 32 KB
    float (*sh_d)[32] = (float(*)[32])(smraw + 32768);    // 2 KB
    int   (*sh_i)[32] = (int(*)[32])(smraw + 34816);      // 2 KB
    int tpb = U / 32;
    int b = bid / tpb;
    int xt = bid - b * tpb;
    const float4* onb = (const float4*)(xc_on + (size_t)b * S * 2);
    for (int i = tid; i < S / 2; i += 256) on[i] = onb[i];
    __syncthreads();
    int part = tid >> 4;
    int ug   = tid & 15;
    int u0 = xt * 32 + ug * 2;
    const float2* offb = (const float2*)(xc_off + (size_t)b * U * 2);
    float2 pA = offb[u0], pB = offb[u0 + 1];
    int h0 = part * (S / 32), h1 = h0 + (S / 32);
    float dA0 = FLT_MAX, dA1 = FLT_MAX, dB0 = FLT_MAX, dB1 = FLT_MAX;
    int iA0 = 0, iA1 = 0, iB0 = 0, iB1 = 0;
    for (int h = h0; h < h1; ++h) {
        float4 cc = on[h];
        int s = h * 2;
        float a0 = fabsf(pA.x - cc.x) + fabsf(pA.y - cc.y);
        float a1 = fabsf(pA.x - cc.z) + fabsf(pA.y - cc.w);
        float b0 = fabsf(pB.x - cc.x) + fabsf(pB.y - cc.y);
        float b1 = fabsf(pB.x - cc.z) + fabsf(pB.y - cc.w);
        if (a0 < dA0) { dA0 = a0; iA0 = s; }
        if (a1 < dA1) { dA1 = a1; iA1 = s + 1; }
        if (b0 < dB0) { dB0 = b0; iB0 = s; }
        if (b1 < dB1) { dB1 = b1; iB1 = s + 1; }
    }
    lexmin(dA0, iA0, dA1, iA1);
    lexmin(dB0, iB0, dB1, iB1);
    sh_d[part][ug * 2] = dA0;     sh_i[part][ug * 2] = iA0;
    sh_d[part][ug * 2 + 1] = dB0; sh_i[part][ug * 2 + 1] = iB0;
    __syncthreads();
    if (tid < 32) {
        float d = sh_d[0][tid]; int i = sh_i[0][tid];
#pragma unroll
        for (int pp = 1; pp < 16; ++pp) lexmin(d, i, sh_d[pp][tid], sh_i[pp][tid]);
        nearest[b * U + xt * 32 + tid] = i;
    }
}

// ---------------------------------------------------------------------------
// K2: blocks 0..B-1 = per-batch CSR build; blocks B.. = MFMA projection tiles
// ---------------------------------------------------------------------------
__global__ __launch_bounds__(256) void proj_csr_kernel(
        const float* __restrict__ latents, const float* __restrict__ zc_off,
        const float* __restrict__ zc_on, const float* __restrict__ fake,
        const int* __restrict__ ignore, const ushort_t* __restrict__ WT,
        ushort_t* __restrict__ Qpre, ushort_t* __restrict__ Koff,
        ushort_t* __restrict__ Voff, ushort_t* __restrict__ Kon,
        ushort_t* __restrict__ Von,
        const int* __restrict__ nearest, int* __restrict__ offsets,
        int* __restrict__ tokens, int S, int U, int B) {
    __shared__ __align__(16) char sm[81920];   // 80 KB -> 2 blocks/CU
    const int BU = B * U;
    const int tid = threadIdx.x;

    if (blockIdx.x < (unsigned)B) {
        int b = blockIdx.x;
        int* cnt  = (int*)sm;                  // S ints (16 KB)
        int* part = (int*)(sm + S * 4);        // 1 KB
        const int* nb = nearest + (size_t)b * U;
        for (int s = tid; s < S; s += 256) cnt[s] = 0;
        __syncthreads();
        for (int i = tid; i < U; i += 256) atomicAdd(&cnt[nb[i]], 1);
        __syncthreads();
        const int items = S / 256;             // 16
        int base = tid * items;
        int sum = 0;
        for (int i = 0; i < items; ++i) sum += cnt[base + i];
        part[tid] = sum;
        __syncthreads();
        for (int off = 1; off < 256; off <<= 1) {
            int v = (tid >= off) ? part[tid - off] : 0;
            __syncthreads();
            part[tid] += v;
            __syncthreads();
        }
        int run = b * U + ((tid == 0) ? 0 : part[tid - 1]);
        for (int i = 0; i < items; ++i) {
            int c = cnt[base + i];
            offsets[b * S + base + i] = run;
            cnt[base + i] = run;               // becomes the cursor
            run += c;
        }
        if (b == B - 1 && tid == 255) offsets[B * S] = B * U;
        __syncthreads();
        for (int i = tid; i < U; i += 256) {
            int pos = atomicAdd(&cnt[nb[i]], 1);
            tokens[pos] = i;
        }
        return;
    }

    char* AsmB  = sm;            // 16 KB
    char* Wsm0B = sm + 16384;    // 32 KB
    char* Wsm1B = sm + 49152;    // 32 KB
    const int lane = tid & 63, wv = tid >> 6;
    const int nQ = S / 64, nOff = BU / 64;
    int t = blockIdx.x - B;
    const ushort_t* WqT = WT;
    const ushort_t* WkT = WT + 16384;
    const ushort_t* WvT = WT + 32768;

    if (t < nQ) {
        int row0 = t * 64;
        stage_A_f32(AsmB, latents + (size_t)row0 * E_DIM, nullptr, false, tid);
        stage_WT(Wsm0B, WqT, tid);
        __syncthreads();
        f32x4 acc[8]; ZERO_ACC(acc);
        mma_16x128(AsmB, Wsm0B, wv, lane, acc);
        epi_bf16(Qpre, row0, wv, lane, acc);
        return;
    }
    bool offg = (t < nQ + nOff);
    int tt = offg ? (t - nQ) : (t - nQ - nOff);
    int row0 = tt * 64;
    const float* A = offg ? zc_off : zc_on;
    bool ign = (!offg) && (*ignore != 0);
    ushort_t* C0 = offg ? Koff : Kon;
    ushort_t* C1 = offg ? Voff : Von;
    stage_A_f32(AsmB, A + (size_t)row0 * E_DIM, fake, ign, tid);
    stage_WT(Wsm0B, WkT, tid);
    stage_WT(Wsm1B, WvT, tid);
    __syncthreads();
    f32x4 acc0[8], acc1[8]; ZERO_ACC(acc0); ZERO_ACC(acc1);
    mma_16x128_dual(AsmB, Wsm0B, Wsm1B, wv, lane, acc0, acc1);
    epi_bf16(C0, row0, wv, lane, acc0);
    epi_bf16(C1, row0, wv, lane, acc1);
}

// ---------------------------------------------------------------------------
// K3: fused attention + output projection. 512 threads (8 waves), 64 cells
//     per block. Wave w computes 8 cells into a swizzled LDS A-tile, then all
//     8 waves MFMA the tile against Wo (rows split 4x, cols split 2x).
// ---------------------------------------------------------------------------
__global__ __launch_bounds__(512) void attn_gemmO_kernel(
        const ushort_t* __restrict__ Qpre,
        const ushort_t* __restrict__ Koff, const ushort_t* __restrict__ Voff,
        const ushort_t* __restrict__ Kon, const ushort_t* __restrict__ Von,
        const int* __restrict__ offsets, const int* __restrict__ tokens,
        const ushort_t* __restrict__ WoT, float* __restrict__ out, int S, int U) {
    __shared__ __align__(16) char sm[49152];   // 16 KB A-tile + 32 KB Wo
    char* AsmB = sm;
    char* WsmB = sm + 16384;
    const int tid = threadIdx.x;
    const int w = tid >> 6;            // 0..7
    const int lane = tid & 63;
    const int row0 = blockIdx.x * 64;

    // stage WoT (2048 uint4 over 512 threads) — issued before attn, overlaps
#pragma unroll
    for (int i = 0; i < 4; ++i) {
        int gb = (tid + i * 512) * 16;
        int n = gb >> 8, cb = gb & 255;
        uint4 v = *(const uint4*)((const char*)WoT + gb);
        *(uint4*)(WsmB + n * 256 + (cb ^ ((n & 7) << 4))) = v;
    }

    // ---- attention: 8 cells per wave ----
    for (int i = 0; i < 8; ++i) {
        int r = w * 8 + i;             // row in tile
        int c = row0 + r;              // global cell
        int b = c / S;
        int cl = c - b * S;
        unsigned int qw = ((const unsigned int*)(Qpre + (size_t)cl * E_DIM))[lane];
        float q0 = bf2f(qw & 0xffffu) * 0.25f;   // 1/sqrt(dh) folded in
        float q1 = bf2f(qw >> 16) * 0.25f;
        unsigned int kw = ((const unsigned int*)(Kon + (size_t)c * E_DIM))[lane];
        float pp = q0 * bf2f(kw & 0xffffu) + q1 * bf2f(kw >> 16);
        pp += __shfl_xor(pp, 4, 8);
        pp += __shfl_xor(pp, 2, 8);
        pp += __shfl_xor(pp, 1, 8);
        unsigned int vw = ((const unsigned int*)(Von + (size_t)c * E_DIM))[lane];
        float mm = pp, ll = 1.f;
        float o0 = bf2f(vw & 0xffffu), o1 = bf2f(vw >> 16);
        int beg = offsets[c], end = offsets[c + 1];
        for (int t = beg; t < end; ++t) {
            int u = tokens[t];
            size_t rr = ((size_t)b * U + u) * E_DIM;
            unsigned int kw2 = ((const unsigned int*)(Koff + rr))[lane];
            unsigned int vw2 = ((const unsigned int*)(Voff + rr))[lane];
            float p2 = q0 * bf2f(kw2 & 0xffffu) + q1 * bf2f(kw2 >> 16);
            p2 += __shfl_xor(p2, 4, 8);
            p2 += __shfl_xor(p2, 2, 8);
            p2 += __shfl_xor(p2, 1, 8);
            float v0 = bf2f(vw2 & 0xffffu), v1 = bf2f(vw2 >> 16);
            float nm = fmaxf(mm, p2);
            float f = __expf(mm - nm), wgt = __expf(p2 - nm);
            ll = ll * f + wgt;
            o0 = o0 * f + wgt * v0;
            o1 = o1 * f + wgt * v1;
            mm = nm;
        }
        float inv = 1.f / ll;
        unsigned int res = (unsigned int)f2bf(o0 * inv) | ((unsigned int)f2bf(o1 * inv) << 16);
        // write into swizzled A-tile position (layout-compatible with mma read)
        *(unsigned int*)(AsmB + r * 256 + ((4 * lane) ^ ((r & 7) << 4))) = res;
    }
    __syncthreads();

    // ---- output GEMM: wave w -> rows (w&3)*16.., cols (w>>2)*64.. ----
    const int wvr = w & 3;
    const int nh = w >> 2;
    const int l15 = lane & 15, kg = lane >> 4;
    f32x4 acc[4];
#pragma unroll
    for (int j = 0; j < 4; ++j) acc[j] = (f32x4){0.f, 0.f, 0.f, 0.f};
    int r = wvr * 16 + l15;
#pragma unroll
    for (int kc = 0; kc < 4; ++kc) {
        int kb = (kc * 32 + kg * 8) * 2;
        bf16x8 a = *(const bf16x8*)(AsmB + r * 256 + (kb ^ ((r & 7) << 4)));
#pragma unroll
        for (int j = 0; j < 4; ++j) {
            int n = (nh * 4 + j) * 16 + l15;
            bf16x8 b = *(const bf16x8*)(WsmB + n * 256 + (kb ^ ((n & 7) << 4)));
            acc[j] = __builtin_amdgcn_mfma_f32_16x16x32_bf16(a, b, acc[j], 0, 0, 0);
        }
    }
    int rbase = row0 + wvr * 16 + kg * 4;
#pragma unroll
    for (int rr = 0; rr < 4; ++rr) {
        float* dst = out + (size_t)(rbase + rr) * E_DIM + nh * 64 + l15;
#pragma unroll
        for (int j = 0; j < 4; ++j) dst[j * 16] = acc[j][rr];
    }
}

// ---------------------------------------------------------------------------
extern "C" void kernel_launch(void* const* d_in, const int* in_sizes, int n_in,
                              void* d_out, int out_size, void* d_ws, size_t ws_size,
                              hipStream_t stream) {
    const float* xc_off  = (const float*)d_in[0];
    const float* xc_on   = (const float*)d_in[1];
    const float* zc_off  = (const float*)d_in[2];
    const float* zc_on   = (const float*)d_in[3];
    const float* latents = (const float*)d_in[4];
    const float* fake    = (const float*)d_in[5];
    const float* Wq      = (const float*)d_in[6];
    const float* Wk      = (const float*)d_in[7];
    const float* Wv      = (const float*)d_in[8];
    const float* Wo      = (const float*)d_in[9];
    const int*   ignore  = (const int*)d_in[10];

    const int E = in_sizes[5];              // 128
    const int S = in_sizes[4] / E;          // 4096
    const int B = in_sizes[1] / (S * 2);    // 4
    const int U = in_sizes[0] / (B * 2);    // 4096
    const int BS = B * S, BU = B * U;

    char* ws = (char*)d_ws;
    size_t off = 0;
    auto alloc = [&](size_t bytes) {
        size_t r = off;
        off += (bytes + 255) & ~(size_t)255;
        return r;
    };
    ushort_t* WT      = (ushort_t*)(ws + alloc((size_t)4 * E * E * 2));
    int*      nearest = (int*)(ws + alloc((size_t)BU * 4));
    int*      offsets = (int*)(ws + alloc((size_t)(BS + 1) * 4));
    int*      tokens  = (int*)(ws + alloc((size_t)BU * 4));
    ushort_t* Qpre    = (ushort_t*)(ws + alloc((size_t)S * E * 2));
    ushort_t* Koff    = (ushort_t*)(ws + alloc((size_t)BU * E * 2));
    ushort_t* Voff    = (ushort_t*)(ws + alloc((size_t)BU * E * 2));
    ushort_t* Kon     = (ushort_t*)(ws + alloc((size_t)BS * E * 2));
    ushort_t* Von     = (ushort_t*)(ws + alloc((size_t)BS * E * 2));

    const int NB = (U / 32) * B;            // 512 nearest blocks
    pre_kernel<<<NB + 64, 256, 0, stream>>>(xc_off, xc_on, Wq, Wk, Wv, Wo,
                                            WT, nearest, U, S, B);

    const int ntile = S / 64 + BU / 64 + BS / 64;   // 576
    proj_csr_kernel<<<ntile + B, 256, 0, stream>>>(latents, zc_off, zc_on, fake, ignore,
                                                   WT, Qpre, Koff, Voff, Kon, Von,
                                                   nearest, offsets, tokens, S, U, B);

    attn_gemmO_kernel<<<BS / 64, 512, 0, stream>>>(Qpre, Koff, Voff, Kon, Von,
                                                   offsets, tokens, WT + 3 * E * E,
                                                   (float*)d_out, S, U);
}

// Round 11
// 135.176 us; speedup vs baseline: 1.0484x; 1.0484x over previous
//
#include <hip/hip_runtime.h>
#include <math.h>
#include <float.h>

#define E_DIM 128
typedef unsigned short ushort_t;
typedef __bf16 bf16x8 __attribute__((ext_vector_type(8)));
typedef float  f32x4  __attribute__((ext_vector_type(4)));

__device__ inline ushort_t f2bf(float f) {
    union { float f; unsigned int u; } x; x.f = f;
    unsigned int r = x.u + 0x7fffu + ((x.u >> 16) & 1u);   // RNE
    return (ushort_t)(r >> 16);
}
__device__ inline float bf2f(unsigned int hi16) {
    union { unsigned int u; float f; } x; x.u = hi16 << 16;
    return x.f;
}
__device__ inline void lexmin(float& d, int& i, float d2, int i2) {
    if (d2 < d || (d2 == d && i2 < i)) { d = d2; i = i2; }
}

// ---- MFMA tile helpers (64 rows x 128 cols, 4 waves, LDS XOR-swizzled) ----
__device__ inline void stage_A_f32(char* AsmB, const float* abase, const float* fake,
                                   bool ign, int tid) {
#pragma unroll
    for (int i = 0; i < 8; ++i) {
        int f = (tid + i * 256) * 4;
        int r = f >> 7, c = f & 127;
        float4 v = *(const float4*)(ign ? (fake + c) : (abase + f));
        unsigned int lo = (unsigned int)f2bf(v.x) | ((unsigned int)f2bf(v.y) << 16);
        unsigned int hi = (unsigned int)f2bf(v.z) | ((unsigned int)f2bf(v.w) << 16);
        *(uint2*)(AsmB + r * 256 + ((c * 2) ^ ((r & 7) << 4))) = make_uint2(lo, hi);
    }
}

// stage pre-transposed bf16 W (n-major [128][128]) -> swizzled LDS (256 thr)
__device__ inline void stage_WT(char* WsmB, const ushort_t* Wt, int tid) {
#pragma unroll
    for (int i = 0; i < 8; ++i) {
        int gb = (tid + i * 256) * 16;
        int n = gb >> 8, cb = gb & 255;
        uint4 v = *(const uint4*)((const char*)Wt + gb);
        *(uint4*)(WsmB + n * 256 + (cb ^ ((n & 7) << 4))) = v;
    }
}

__device__ inline void mma_16x128(char* AsmB, char* WsmB, int wv, int lane, f32x4 acc[8]) {
    int l15 = lane & 15, kg = lane >> 4;
    int r = wv * 16 + l15;
#pragma unroll
    for (int kc = 0; kc < 4; ++kc) {
        int kb = (kc * 32 + kg * 8) * 2;
        bf16x8 a = *(const bf16x8*)(AsmB + r * 256 + (kb ^ ((r & 7) << 4)));
#pragma unroll
        for (int nf = 0; nf < 8; ++nf) {
            int n = nf * 16 + l15;
            bf16x8 b = *(const bf16x8*)(WsmB + n * 256 + (kb ^ ((n & 7) << 4)));
            acc[nf] = __builtin_amdgcn_mfma_f32_16x16x32_bf16(a, b, acc[nf], 0, 0, 0);
        }
    }
}

__device__ inline void mma_16x128_dual(char* AsmB, char* Wsm0B, char* Wsm1B,
                                       int wv, int lane, f32x4 acc0[8], f32x4 acc1[8]) {
    int l15 = lane & 15, kg = lane >> 4;
    int r = wv * 16 + l15;
#pragma unroll
    for (int kc = 0; kc < 4; ++kc) {
        int kb = (kc * 32 + kg * 8) * 2;
        bf16x8 a = *(const bf16x8*)(AsmB + r * 256 + (kb ^ ((r & 7) << 4)));
#pragma unroll
        for (int nf = 0; nf < 8; ++nf) {
            int n = nf * 16 + l15;
            int nb = (kb ^ ((n & 7) << 4));
            bf16x8 b0 = *(const bf16x8*)(Wsm0B + n * 256 + nb);
            acc0[nf] = __builtin_amdgcn_mfma_f32_16x16x32_bf16(a, b0, acc0[nf], 0, 0, 0);
            bf16x8 b1 = *(const bf16x8*)(Wsm1B + n * 256 + nb);
            acc1[nf] = __builtin_amdgcn_mfma_f32_16x16x32_bf16(a, b1, acc1[nf], 0, 0, 0);
        }
    }
}

__device__ inline void epi_bf16(ushort_t* C, int row0, int wv, int lane, f32x4 acc[8]) {
    int l15 = lane & 15, kg = lane >> 4;
    int rbase = row0 + wv * 16 + kg * 4;
#pragma unroll
    for (int rr = 0; rr < 4; ++rr) {
        ushort_t* dst = C + (size_t)(rbase + rr) * E_DIM + l15;
#pragma unroll
        for (int nf = 0; nf < 8; ++nf) dst[nf * 16] = f2bf(acc[nf][rr]);
    }
}

__device__ inline void epi_f32(float* C, int row0, int wv, int lane, f32x4 acc[8]) {
    int l15 = lane & 15, kg = lane >> 4;
    int rbase = row0 + wv * 16 + kg * 4;
#pragma unroll
    for (int rr = 0; rr < 4; ++rr) {
        float* dst = C + (size_t)(rbase + rr) * E_DIM + l15;
#pragma unroll
        for (int nf = 0; nf < 8; ++nf) dst[nf * 16] = acc[nf][rr];
    }
}

#define ZERO_ACC(a) do { _Pragma("unroll") for (int _i = 0; _i < 8; ++_i) \
    (a)[_i] = (f32x4){0.f, 0.f, 0.f, 0.f}; } while (0)

// ---------------------------------------------------------------------------
// K1: blocks [0, NB): nearest (L1 argmin, first-min tie-break)
//     blocks [NB, NB+64): fp32->bf16 n-major weight transpose
// ---------------------------------------------------------------------------
__global__ __launch_bounds__(256) void pre_kernel(
        const float* __restrict__ xc_off, const float* __restrict__ xc_on,
        const float* __restrict__ Wq, const float* __restrict__ Wk,
        const float* __restrict__ Wv, const float* __restrict__ Wo,
        ushort_t* __restrict__ WT, int* __restrict__ nearest, int U, int S, int B) {
    __shared__ __align__(16) char smraw[36928];
    const int NB = (U / 32) * B;
    int bid = blockIdx.x;
    int tid = threadIdx.x;
    if (bid >= NB) {
        int base = (bid - NB) * 1024 + tid;
#pragma unroll
        for (int j = 0; j < 4; ++j) {
            int idx = base + j * 256;
            int w = idx >> 14;
            int rem = idx & 16383;
            int k = rem >> 7, n = rem & 127;
            const float* src = (w == 0) ? Wq : (w == 1) ? Wk : (w == 2) ? Wv : Wo;
            WT[(size_t)w * 16384 + n * E_DIM + k] = f2bf(src[k * E_DIM + n]);
        }
        return;
    }
    float4* on = (float4*)smraw;                          // 32 KB
    float (*sh_d)[32] = (float(*)[32])(smraw + 32768);    // 2 KB
    int   (*sh_i)[32] = (int(*)[32])(smraw + 34816);      // 2 KB
    int tpb = U / 32;
    int b = bid / tpb;
    int xt = bid - b * tpb;
    const float4* onb = (const float4*)(xc_on + (size_t)b * S * 2);
    for (int i = tid; i < S / 2; i += 256) on[i] = onb[i];
    __syncthreads();
    int part = tid >> 4;
    int ug   = tid & 15;
    int u0 = xt * 32 + ug * 2;
    const float2* offb = (const float2*)(xc_off + (size_t)b * U * 2);
    float2 pA = offb[u0], pB = offb[u0 + 1];
    int h0 = part * (S / 32), h1 = h0 + (S / 32);
    float dA0 = FLT_MAX, dA1 = FLT_MAX, dB0 = FLT_MAX, dB1 = FLT_MAX;
    int iA0 = 0, iA1 = 0, iB0 = 0, iB1 = 0;
    for (int h = h0; h < h1; ++h) {
        float4 cc = on[h];
        int s = h * 2;
        float a0 = fabsf(pA.x - cc.x) + fabsf(pA.y - cc.y);
        float a1 = fabsf(pA.x - cc.z) + fabsf(pA.y - cc.w);
        float b0 = fabsf(pB.x - cc.x) + fabsf(pB.y - cc.y);
        float b1 = fabsf(pB.x - cc.z) + fabsf(pB.y - cc.w);
        if (a0 < dA0) { dA0 = a0; iA0 = s; }
        if (a1 < dA1) { dA1 = a1; iA1 = s + 1; }
        if (b0 < dB0) { dB0 = b0; iB0 = s; }
        if (b1 < dB1) { dB1 = b1; iB1 = s + 1; }
    }
    lexmin(dA0, iA0, dA1, iA1);
    lexmin(dB0, iB0, dB1, iB1);
    sh_d[part][ug * 2] = dA0;     sh_i[part][ug * 2] = iA0;
    sh_d[part][ug * 2 + 1] = dB0; sh_i[part][ug * 2 + 1] = iB0;
    __syncthreads();
    if (tid < 32) {
        float d = sh_d[0][tid]; int i = sh_i[0][tid];
#pragma unroll
        for (int pp = 1; pp < 16; ++pp) lexmin(d, i, sh_d[pp][tid], sh_i[pp][tid]);
        nearest[b * U + xt * 32 + tid] = i;
    }
}

// ---------------------------------------------------------------------------
// K2: blocks 0..B-1 = per-batch CSR build; blocks B.. = MFMA projection tiles
// ---------------------------------------------------------------------------
__global__ __launch_bounds__(256) void proj_csr_kernel(
        const float* __restrict__ latents, const float* __restrict__ zc_off,
        const float* __restrict__ zc_on, const float* __restrict__ fake,
        const int* __restrict__ ignore, const ushort_t* __restrict__ WT,
        ushort_t* __restrict__ Qpre, ushort_t* __restrict__ Koff,
        ushort_t* __restrict__ Voff, ushort_t* __restrict__ Kon,
        ushort_t* __restrict__ Von,
        const int* __restrict__ nearest, int* __restrict__ offsets,
        int* __restrict__ tokens, int S, int U, int B) {
    __shared__ __align__(16) char sm[81920];   // 80 KB -> 2 blocks/CU
    const int BU = B * U;
    const int tid = threadIdx.x;

    if (blockIdx.x < (unsigned)B) {
        int b = blockIdx.x;
        int* cnt  = (int*)sm;                  // S ints (16 KB)
        int* part = (int*)(sm + S * 4);        // 1 KB
        const int* nb = nearest + (size_t)b * U;
        for (int s = tid; s < S; s += 256) cnt[s] = 0;
        __syncthreads();
        for (int i = tid; i < U; i += 256) atomicAdd(&cnt[nb[i]], 1);
        __syncthreads();
        const int items = S / 256;             // 16
        int base = tid * items;
        int sum = 0;
        for (int i = 0; i < items; ++i) sum += cnt[base + i];
        part[tid] = sum;
        __syncthreads();
        for (int off = 1; off < 256; off <<= 1) {
            int v = (tid >= off) ? part[tid - off] : 0;
            __syncthreads();
            part[tid] += v;
            __syncthreads();
        }
        int run = b * U + ((tid == 0) ? 0 : part[tid - 1]);
        for (int i = 0; i < items; ++i) {
            int c = cnt[base + i];
            offsets[b * S + base + i] = run;
            cnt[base + i] = run;               // becomes the cursor
            run += c;
        }
        if (b == B - 1 && tid == 255) offsets[B * S] = B * U;
        __syncthreads();
        for (int i = tid; i < U; i += 256) {
            int pos = atomicAdd(&cnt[nb[i]], 1);
            tokens[pos] = i;
        }
        return;
    }

    char* AsmB  = sm;            // 16 KB
    char* Wsm0B = sm + 16384;    // 32 KB
    char* Wsm1B = sm + 49152;    // 32 KB
    const int lane = tid & 63, wv = tid >> 6;
    const int nQ = S / 64, nOff = BU / 64;
    int t = blockIdx.x - B;
    const ushort_t* WqT = WT;
    const ushort_t* WkT = WT + 16384;
    const ushort_t* WvT = WT + 32768;

    if (t < nQ) {
        int row0 = t * 64;
        stage_A_f32(AsmB, latents + (size_t)row0 * E_DIM, nullptr, false, tid);
        stage_WT(Wsm0B, WqT, tid);
        __syncthreads();
        f32x4 acc[8]; ZERO_ACC(acc);
        mma_16x128(AsmB, Wsm0B, wv, lane, acc);
        epi_bf16(Qpre, row0, wv, lane, acc);
        return;
    }
    bool offg = (t < nQ + nOff);
    int tt = offg ? (t - nQ) : (t - nQ - nOff);
    int row0 = tt * 64;
    const float* A = offg ? zc_off : zc_on;
    bool ign = (!offg) && (*ignore != 0);
    ushort_t* C0 = offg ? Koff : Kon;
    ushort_t* C1 = offg ? Voff : Von;
    stage_A_f32(AsmB, A + (size_t)row0 * E_DIM, fake, ign, tid);
    stage_WT(Wsm0B, WkT, tid);
    stage_WT(Wsm1B, WvT, tid);
    __syncthreads();
    f32x4 acc0[8], acc1[8]; ZERO_ACC(acc0); ZERO_ACC(acc1);
    mma_16x128_dual(AsmB, Wsm0B, Wsm1B, wv, lane, acc0, acc1);
    epi_bf16(C0, row0, wv, lane, acc0);
    epi_bf16(C1, row0, wv, lane, acc1);
}

// ---------------------------------------------------------------------------
// K3: per-cell masked MHA (1 wave per cell, online softmax, bf16 K/V).
//     Software-pipelined: token t+1's K/V gather is issued before token t's
//     softmax chain, hiding ~200cy L2 latency under the VALU work.
// ---------------------------------------------------------------------------
__global__ __launch_bounds__(256) void attn_kernel(
        const ushort_t* __restrict__ Qpre,
        const ushort_t* __restrict__ Koff, const ushort_t* __restrict__ Voff,
        const ushort_t* __restrict__ Kon, const ushort_t* __restrict__ Von,
        const int* __restrict__ offsets, const int* __restrict__ tokens,
        ushort_t* __restrict__ AO, int S, int U) {
    int wv = threadIdx.x >> 6;
    int lane = threadIdx.x & 63;
    int c = blockIdx.x * 4 + wv;
    int b = c / S;
    int cl = c - b * S;

    unsigned int qw = ((const unsigned int*)(Qpre + (size_t)cl * E_DIM))[lane];
    float q0 = bf2f(qw & 0xffffu) * 0.25f;   // 1/sqrt(dh) folded in
    float q1 = bf2f(qw >> 16) * 0.25f;

    unsigned int kw = ((const unsigned int*)(Kon + (size_t)c * E_DIM))[lane];
    float pp = q0 * bf2f(kw & 0xffffu) + q1 * bf2f(kw >> 16);
    pp += __shfl_xor(pp, 4, 8);
    pp += __shfl_xor(pp, 2, 8);
    pp += __shfl_xor(pp, 1, 8);
    unsigned int vw = ((const unsigned int*)(Von + (size_t)c * E_DIM))[lane];
    float mm = pp, ll = 1.f;
    float o0 = bf2f(vw & 0xffffu), o1 = bf2f(vw >> 16);

    int beg = offsets[c], end = offsets[c + 1];
    unsigned int kpre = 0, vpre = 0;
    if (beg < end) {
        size_t rr = ((size_t)b * U + tokens[beg]) * E_DIM;
        kpre = ((const unsigned int*)(Koff + rr))[lane];
        vpre = ((const unsigned int*)(Voff + rr))[lane];
    }
    for (int t = beg; t < end; ++t) {
        unsigned int kcur = kpre, vcur = vpre;
        if (t + 1 < end) {                      // prefetch next token's row
            size_t rr = ((size_t)b * U + tokens[t + 1]) * E_DIM;
            kpre = ((const unsigned int*)(Koff + rr))[lane];
            vpre = ((const unsigned int*)(Voff + rr))[lane];
        }
        float p2 = q0 * bf2f(kcur & 0xffffu) + q1 * bf2f(kcur >> 16);
        p2 += __shfl_xor(p2, 4, 8);
        p2 += __shfl_xor(p2, 2, 8);
        p2 += __shfl_xor(p2, 1, 8);
        float v0 = bf2f(vcur & 0xffffu), v1 = bf2f(vcur >> 16);
        float nm = fmaxf(mm, p2);
        float f = __expf(mm - nm), w = __expf(p2 - nm);
        ll = ll * f + w;
        o0 = o0 * f + w * v0;
        o1 = o1 * f + w * v1;
        mm = nm;
    }
    float inv = 1.f / ll;
    ((unsigned int*)(AO + (size_t)c * E_DIM))[lane] =
        (unsigned int)f2bf(o0 * inv) | ((unsigned int)f2bf(o1 * inv) << 16);
}

// ---------------------------------------------------------------------------
// K4: output projection AO(bf16) @ Wo -> out (fp32)
// ---------------------------------------------------------------------------
__global__ __launch_bounds__(256) void gemmO_kernel(
        const ushort_t* __restrict__ AO, const ushort_t* __restrict__ WoT,
        float* __restrict__ out, int BS) {
    __shared__ __align__(16) char sm[49152];
    char* AsmB = sm;
    char* WsmB = sm + 16384;
    int tid = threadIdx.x, lane = tid & 63, wv = tid >> 6;
    int row0 = blockIdx.x * 64;
    const char* abase = (const char*)(AO + (size_t)row0 * E_DIM);
#pragma unroll
    for (int i = 0; i < 4; ++i) {
        int gb = (tid + i * 256) * 16;
        int r = gb >> 8, cb = gb & 255;
        uint4 v = *(const uint4*)(abase + gb);
        *(uint4*)(AsmB + r * 256 + (cb ^ ((r & 7) << 4))) = v;
    }
    stage_WT(WsmB, WoT, tid);
    __syncthreads();
    f32x4 acc[8]; ZERO_ACC(acc);
    mma_16x128(AsmB, WsmB, wv, lane, acc);
    epi_f32(out, row0, wv, lane, acc);
}

// ---------------------------------------------------------------------------
extern "C" void kernel_launch(void* const* d_in, const int* in_sizes, int n_in,
                              void* d_out, int out_size, void* d_ws, size_t ws_size,
                              hipStream_t stream) {
    const float* xc_off  = (const float*)d_in[0];
    const float* xc_on   = (const float*)d_in[1];
    const float* zc_off  = (const float*)d_in[2];
    const float* zc_on   = (const float*)d_in[3];
    const float* latents = (const float*)d_in[4];
    const float* fake    = (const float*)d_in[5];
    const float* Wq      = (const float*)d_in[6];
    const float* Wk      = (const float*)d_in[7];
    const float* Wv      = (const float*)d_in[8];
    const float* Wo      = (const float*)d_in[9];
    const int*   ignore  = (const int*)d_in[10];

    const int E = in_sizes[5];              // 128
    const int S = in_sizes[4] / E;          // 4096
    const int B = in_sizes[1] / (S * 2);    // 4
    const int U = in_sizes[0] / (B * 2);    // 4096
    const int BS = B * S, BU = B * U;

    char* ws = (char*)d_ws;
    size_t off = 0;
    auto alloc = [&](size_t bytes) {
        size_t r = off;
        off += (bytes + 255) & ~(size_t)255;
        return r;
    };
    ushort_t* WT      = (ushort_t*)(ws + alloc((size_t)4 * E * E * 2));
    int*      nearest = (int*)(ws + alloc((size_t)BU * 4));
    int*      offsets = (int*)(ws + alloc((size_t)(BS + 1) * 4));
    int*      tokens  = (int*)(ws + alloc((size_t)BU * 4));
    ushort_t* Qpre    = (ushort_t*)(ws + alloc((size_t)S * E * 2));
    ushort_t* Koff    = (ushort_t*)(ws + alloc((size_t)BU * E * 2));
    ushort_t* Voff    = (ushort_t*)(ws + alloc((size_t)BU * E * 2));
    ushort_t* Kon     = (ushort_t*)(ws + alloc((size_t)BS * E * 2));
    ushort_t* Von     = (ushort_t*)(ws + alloc((size_t)BS * E * 2));
    ushort_t* AO      = (ushort_t*)(ws + alloc((size_t)BS * E * 2));

    const int NB = (U / 32) * B;            // 512 nearest blocks
    pre_kernel<<<NB + 64, 256, 0, stream>>>(xc_off, xc_on, Wq, Wk, Wv, Wo,
                                            WT, nearest, U, S, B);

    const int ntile = S / 64 + BU / 64 + BS / 64;   // 576
    proj_csr_kernel<<<ntile + B, 256, 0, stream>>>(latents, zc_off, zc_on, fake, ignore,
                                                   WT, Qpre, Koff, Voff, Kon, Von,
                                                   nearest, offsets, tokens, S, U, B);

    attn_kernel<<<BS / 4, 256, 0, stream>>>(Qpre, Koff, Voff, Kon, Von,
                                            offsets, tokens, AO, S, U);

    gemmO_kernel<<<BS / 64, 256, 0, stream>>>(AO, WT + 3 * E * E, (float*)d_out, BS);
}